// Round 1
// baseline (1570.127 us; speedup 1.0000x reference)
//
#include <hip/hip_runtime.h>

// LDN cell: new_state = expm(A) @ state + [inv(A)(expm(A)-I)B] x^T
// expm computed on-device via scaling-and-squaring Taylor (PS scheme) on the
// augmented 513x513 matrix [[A,B],[0,0]] padded to 576x576:
//   expm gives Ad in [0:512,0:512] and Bd = phi1(A)B in column 512 (no solve).
// Chain GEMMs use 3-way bf16 split (6 MFMA products) for f32-equivalent
// accuracy; the big 512x512x65536 GEMM uses plain bf16 MFMA.

#define PDIM 576            // padded expm dim (multiple of 64)
#define PP (PDIM * PDIM)
#define QDIM 512
#define NDIM 65536

typedef __attribute__((ext_vector_type(8))) short short8;   // 8 bf16 (4 VGPRs)
typedef __attribute__((ext_vector_type(4))) short short4v;  // 4 bf16 (8 B)
typedef __attribute__((ext_vector_type(4))) float f32x4;

__device__ __forceinline__ short f2bf(float f) {  // round-to-nearest-even bf16
  unsigned u = __builtin_bit_cast(unsigned, f);
  u += 0x7fffu + ((u >> 16) & 1u);
  return (short)(u >> 16);
}
__device__ __forceinline__ float bf2f(short s) {
  unsigned u = ((unsigned)(unsigned short)s) << 16;
  return __builtin_bit_cast(float, u);
}
__device__ __forceinline__ void split3(float v, short& h, short& m, short& l) {
  h = f2bf(v);
  float r1 = v - bf2f(h);   // exact (Sterbenz)
  m = f2bf(r1);
  float r2 = r1 - bf2f(m);  // exact
  l = f2bf(r2);
}

__device__ __forceinline__ f32x4 MFMA(short8 a, short8 b, f32x4 c) {
  return __builtin_amdgcn_mfma_f32_16x16x32_bf16(a, b, c, 0, 0, 0);
}

// ---------------------------------------------------------------- build M ---
// M = [[A*s, B*s],[0,0]] padded to 576x576, s = DT/2^15 (DT = 1).
__global__ __launch_bounds__(256) void build_M(const float* __restrict__ A,
                                               const float* __restrict__ Bv,
                                               float* __restrict__ M, float scale) {
  int idx = blockIdx.x * 256 + threadIdx.x;
  int i = idx / PDIM, j = idx - i * PDIM;
  float v = 0.f;
  if (i < QDIM) {
    if (j < QDIM) v = A[i * QDIM + j] * scale;
    else if (j == QDIM) v = Bv[i] * scale;
  }
  M[idx] = v;
}

// ----------------------------------------------------------- combine (G3) ---
// Out = cA4*A4 + cM*M + cA2*A2 + cA3*A3 + cI*I   (elementwise)
__global__ __launch_bounds__(256) void combine5(const float* __restrict__ A4,
    const float* __restrict__ M, const float* __restrict__ A2,
    const float* __restrict__ A3, float* __restrict__ Out,
    float cA4, float cM, float cA2, float cA3, float cI) {
  int idx = blockIdx.x * 256 + threadIdx.x;
  int i = idx / PDIM, j = idx - i * PDIM;
  float v = cA4 * A4[idx] + cM * M[idx] + cA2 * A2[idx] + cA3 * A3[idx];
  if (i == j) v += cI;
  Out[idx] = v;
}

// ------------------------------------------------------ chain GEMM (split) ---
// Out = X*Y [+ cI*I + c1*E1 + c2*E2 + c3*E3].  576^3, f32-equivalent accuracy
// via 3-way bf16 split (products hh, hm, mh, hl, lh, mm).
// Block: 64x64 tile, 256 thr = 4 waves, each wave 32x32 (2x2 MFMA tiles).
__global__ __launch_bounds__(256) void gemm576(const float* __restrict__ X,
    const float* __restrict__ Y, float* __restrict__ Out,
    const float* __restrict__ E1, const float* __restrict__ E2,
    const float* __restrict__ E3,
    float cI, float c1, float c2, float c3, int use_e) {
  __shared__ short Xs[3][64][48];  // [plane][m][k], row stride 96B (16B-aligned)
  __shared__ short Ys[3][64][48];  // [plane][n][k] (transposed staging)
  const int tid = threadIdx.x;
  const int lane = tid & 63, w = tid >> 6;
  const int m0 = blockIdx.x * 64, n0 = blockIdx.y * 64;
  const int moff = (w >> 1) * 32, noff = (w & 1) * 32;
  const int l15 = lane & 15, quad = lane >> 4;
  f32x4 acc[2][2] = {};

  for (int kb = 0; kb < PDIM; kb += 32) {
    {  // stage X: thread -> (row = t>>2, 8 consecutive k), split into 3 planes
      const int row = tid >> 2, qc = tid & 3;
      const float* src = X + (size_t)(m0 + row) * PDIM + kb + qc * 8;
      float4 u0 = *(const float4*)(src);
      float4 u1 = *(const float4*)(src + 4);
      float vv[8] = {u0.x, u0.y, u0.z, u0.w, u1.x, u1.y, u1.z, u1.w};
      short8 h, m, l;
#pragma unroll
      for (int e = 0; e < 8; e++) {
        short hh, mm, ll; split3(vv[e], hh, mm, ll);
        h[e] = hh; m[e] = mm; l[e] = ll;
      }
      *(short8*)&Xs[0][row][qc * 8] = h;
      *(short8*)&Xs[1][row][qc * 8] = m;
      *(short8*)&Xs[2][row][qc * 8] = l;
    }
    {  // stage Y transposed: thread -> (kq = t>>5, n = t&31 (+32)); 4 k each
      const int kq = tid >> 5, nl = tid & 31;
#pragma unroll
      for (int half = 0; half < 2; half++) {
        const int n = nl + half * 32;
        short4v hp, mp, lp;
#pragma unroll
        for (int r = 0; r < 4; r++) {
          float v = Y[(size_t)(kb + kq * 4 + r) * PDIM + n0 + n];
          short hh, mm, ll; split3(v, hh, mm, ll);
          hp[r] = hh; mp[r] = mm; lp[r] = ll;
        }
        *(short4v*)&Ys[0][n][kq * 4] = hp;
        *(short4v*)&Ys[1][n][kq * 4] = mp;
        *(short4v*)&Ys[2][n][kq * 4] = lp;
      }
    }
    __syncthreads();
    short8 xa[3][2], yb[3][2];
#pragma unroll
    for (int pl = 0; pl < 3; pl++) {
#pragma unroll
      for (int i = 0; i < 2; i++)
        xa[pl][i] = *(const short8*)&Xs[pl][moff + i * 16 + l15][quad * 8];
#pragma unroll
      for (int j = 0; j < 2; j++)
        yb[pl][j] = *(const short8*)&Ys[pl][noff + j * 16 + l15][quad * 8];
    }
#pragma unroll
    for (int i = 0; i < 2; i++)
#pragma unroll
      for (int j = 0; j < 2; j++) {
        f32x4 a = acc[i][j];
        a = MFMA(xa[0][i], yb[0][j], a);  // hh
        a = MFMA(xa[0][i], yb[1][j], a);  // hm
        a = MFMA(xa[1][i], yb[0][j], a);  // mh
        a = MFMA(xa[0][i], yb[2][j], a);  // hl
        a = MFMA(xa[2][i], yb[0][j], a);  // lh
        a = MFMA(xa[1][i], yb[1][j], a);  // mm
        acc[i][j] = a;
      }
    __syncthreads();
  }
  // epilogue: C/D layout col = lane&15, row = quad*4 + reg
#pragma unroll
  for (int i = 0; i < 2; i++)
#pragma unroll
    for (int j = 0; j < 2; j++) {
      const int gcol = n0 + noff + j * 16 + l15;
#pragma unroll
      for (int r = 0; r < 4; r++) {
        const int grow = m0 + moff + i * 16 + quad * 4 + r;
        const size_t idx = (size_t)grow * PDIM + gcol;
        float v = acc[i][j][r];
        if (use_e) {
          v += c1 * E1[idx] + c2 * E2[idx] + c3 * E3[idx];
          if (grow == gcol) v += cI;
        }
        Out[idx] = v;
      }
    }
}

// ----------------------------------------------------------- main GEMM ------
// out[q][n] = sum_k Ad[q][k] state[k][n] + Bd[q] x[n]
// Ad/Bd live in T (stride PDIM; Bd is column 512). Writes out1 (row-major)
// and out0 (transposed flat) via per-wave LDS transpose chunks.
// Block: 128x128 tile, 4 waves each 64x64 (4x4 MFMA tiles), BK = 32.
__global__ __launch_bounds__(256) void gemm_main(const float* __restrict__ T,
    const float* __restrict__ S, const float* __restrict__ xv,
    float* __restrict__ out0, float* __restrict__ out1) {
  __shared__ short Ah[128][48];        // Ad tile, bf16, [m][k]
  __shared__ short Bs[128][48];        // state tile, bf16, [n][k] transposed
  __shared__ float epi[4][16][65];     // per-wave epilogue transpose chunk
  const int tid = threadIdx.x;
  const int lane = tid & 63, w = tid >> 6;
  const int m0 = blockIdx.x * 128;     // grid.x = 4 (m fastest: L2 reuse of S)
  const int n0 = blockIdx.y * 128;     // grid.y = 512
  const int moff = (w >> 1) * 64, noff = (w & 1) * 64;
  const int l15 = lane & 15, quad = lane >> 4;
  f32x4 acc[4][4] = {};

  for (int kb = 0; kb < QDIM; kb += 32) {
    {  // stage Ad: thread -> (row = t>>1, 16 consecutive k)
      const int row = tid >> 1, half = tid & 1;
      const float* src = T + (size_t)(m0 + row) * PDIM + kb + half * 16;
      float4 u0 = *(const float4*)(src);
      float4 u1 = *(const float4*)(src + 4);
      float4 u2 = *(const float4*)(src + 8);
      float4 u3 = *(const float4*)(src + 12);
      float vv[16] = {u0.x, u0.y, u0.z, u0.w, u1.x, u1.y, u1.z, u1.w,
                      u2.x, u2.y, u2.z, u2.w, u3.x, u3.y, u3.z, u3.w};
      short8 o0, o1;
#pragma unroll
      for (int e = 0; e < 8; e++) { o0[e] = f2bf(vv[e]); o1[e] = f2bf(vv[8 + e]); }
      *(short8*)&Ah[row][half * 16] = o0;
      *(short8*)&Ah[row][half * 16 + 8] = o1;
    }
    {  // stage state transposed: (kq = t>>5, n = t&31 + g*32), 4 k each
      const int kq = tid >> 5, nl = tid & 31;
#pragma unroll
      for (int g = 0; g < 4; g++) {
        const int n = nl + g * 32;
        short4v pk;
#pragma unroll
        for (int r = 0; r < 4; r++)
          pk[r] = f2bf(S[(size_t)(kb + kq * 4 + r) * NDIM + n0 + n]);
        *(short4v*)&Bs[n][kq * 4] = pk;
      }
    }
    __syncthreads();
    short8 af[4], bfr[4];
#pragma unroll
    for (int i = 0; i < 4; i++)
      af[i] = *(const short8*)&Ah[moff + i * 16 + l15][quad * 8];
#pragma unroll
    for (int j = 0; j < 4; j++)
      bfr[j] = *(const short8*)&Bs[noff + j * 16 + l15][quad * 8];
#pragma unroll
    for (int i = 0; i < 4; i++)
#pragma unroll
      for (int j = 0; j < 4; j++)
        acc[i][j] = MFMA(af[i], bfr[j], acc[i][j]);
    __syncthreads();
  }

  // epilogue: per 16-row chunk i, transpose through per-wave LDS slice
  const float xvl = xv[n0 + noff + lane];
#pragma unroll 1
  for (int i = 0; i < 4; i++) {
#pragma unroll
    for (int j = 0; j < 4; j++)
#pragma unroll
      for (int r = 0; r < 4; r++)
        epi[w][quad * 4 + r][j * 16 + l15] = acc[i][j][r];
    const int rowbase = m0 + moff + i * 16;
    // out1 (row-major): 64 consecutive floats per 64-lane store
    for (int rr = 0; rr < 16; rr++) {
      const float bd = T[(size_t)(rowbase + rr) * PDIM + QDIM];
      const float v = epi[w][rr][lane];
      out1[(size_t)(rowbase + rr) * NDIM + (n0 + noff + lane)] = v + bd * xvl;
    }
    // out0 (transposed flat): 16-lane 64B segments, 4 cols per iteration
    const float bdl = T[(size_t)(rowbase + l15) * PDIM + QDIM];
    for (int c4 = 0; c4 < 16; c4++) {
      const int cc = c4 * 4 + quad;
      const float v = epi[w][l15][cc];
      const float xc = xv[n0 + noff + cc];
      out0[(size_t)(n0 + noff + cc) * QDIM + (rowbase + l15)] = v + bdl * xc;
    }
  }
}

// ---------------------------------------------------------------- launch ----
extern "C" void kernel_launch(void* const* d_in, const int* in_sizes, int n_in,
                              void* d_out, int out_size, void* d_ws, size_t ws_size,
                              hipStream_t stream) {
  const float* xv    = (const float*)d_in[0];   // [65536]
  const float* state = (const float*)d_in[1];   // [512, 65536]
  const float* A     = (const float*)d_in[2];   // [512, 512]
  const float* Bv    = (const float*)d_in[3];   // [512, 1]
  float* out0 = (float*)d_out;                  // new_state.T.flatten()
  float* out1 = out0 + (size_t)QDIM * NDIM;     // new_state

  float* W  = (float*)d_ws;                     // 6 * 576^2 f32 = 7.96 MB
  float* M  = W;
  float* A2 = W + (size_t)PP;
  float* A3 = W + (size_t)2 * PP;
  float* A4 = W + (size_t)3 * PP;
  float* Tb = W + (size_t)4 * PP;
  float* Ub = W + (size_t)5 * PP;

  // ||M||_1 = 65536 exactly -> scale 2^-15 gives theta = 2; Taylor-16
  // truncation ~4e-10; 15 squarings recover expm(M).
  const float scale = 1.0f / 32768.0f;
  float c[17];
  { double f = 1.0; c[0] = 1.0f;
    for (int k = 1; k <= 16; k++) { f *= (double)k; c[k] = (float)(1.0 / f); } }

  dim3 g9(9, 9);
  build_M<<<PP / 256, 256, 0, stream>>>(A, Bv, M, scale);
  gemm576<<<g9, 256, 0, stream>>>(M, M, A2, nullptr, nullptr, nullptr, 0, 0, 0, 0, 0);
  gemm576<<<g9, 256, 0, stream>>>(A2, M, A3, nullptr, nullptr, nullptr, 0, 0, 0, 0, 0);
  gemm576<<<g9, 256, 0, stream>>>(A2, A2, A4, nullptr, nullptr, nullptr, 0, 0, 0, 0, 0);
  // Paterson-Stockmeyer: G3 = c16*A4 + C3; then G2, G1, G0 via Horner in A4
  combine5<<<PP / 256, 256, 0, stream>>>(A4, M, A2, A3, Tb,
                                         c[16], c[13], c[14], c[15], c[12]);
  gemm576<<<g9, 256, 0, stream>>>(A4, Tb, Ub, M, A2, A3, c[8], c[9], c[10], c[11], 1);
  gemm576<<<g9, 256, 0, stream>>>(A4, Ub, Tb, M, A2, A3, c[4], c[5], c[6], c[7], 1);
  gemm576<<<g9, 256, 0, stream>>>(A4, Tb, Ub, M, A2, A3, c[0], c[1], c[2], c[3], 1);
  // 15 squarings (ends in Tb after odd count; tracked via pointer swap)
  float* src = Ub; float* dst = Tb;
  for (int i = 0; i < 15; i++) {
    gemm576<<<g9, 256, 0, stream>>>(src, src, dst, nullptr, nullptr, nullptr,
                                    0, 0, 0, 0, 0);
    float* t = src; src = dst; dst = t;
  }
  // src now holds expm of the augmented matrix: Ad = src[0:512,0:512],
  // Bd = src[:,512] (stride PDIM)
  gemm_main<<<dim3(4, 512), 256, 0, stream>>>(src, state, xv, out0, out1);

  (void)in_sizes; (void)n_in; (void)out_size; (void)ws_size;
}